// Round 4
// baseline (424.513 us; speedup 1.0000x reference)
//
#include <hip/hip_runtime.h>
#include <math.h>

typedef _Float16 f16;
typedef _Float16 f16x4 __attribute__((ext_vector_type(4)));
typedef _Float16 f16x8 __attribute__((ext_vector_type(8)));
typedef float f32x4 __attribute__((ext_vector_type(4)));
typedef float f32x8 __attribute__((ext_vector_type(8)));

#define AS1 __attribute__((address_space(1)))
#define AS3 __attribute__((address_space(3)))

__device__ __forceinline__ void gld_lds16(const f16* g, f16* l) {
#if defined(__has_builtin) && __has_builtin(__builtin_amdgcn_global_load_lds)
    __builtin_amdgcn_global_load_lds((const AS1 void*)g, (AS3 void*)l, 16, 0, 0);
#else
    *(uint4*)l = *(const uint4*)g;
#endif
}

// ---------------- pre-pass 1: input [128,256,20,20] f32 -> [128,20,20,256] f16 ----------
__global__ __launch_bounds__(256) void transpose_input(
    const float* __restrict__ inp, f16* __restrict__ out)
{
    const int b = blockIdx.x, c0 = blockIdx.y * 32, p0 = blockIdx.z * 32;
    const int tx = threadIdx.x, ty = threadIdx.y;   // 32 x 8
    __shared__ float t[32][33];
#pragma unroll
    for (int j = 0; j < 4; ++j) {
        int c = ty + j * 8, p = p0 + tx;
        if (p < 400) t[c][tx] = inp[((size_t)b * 256 + c0 + c) * 400 + p];
    }
    __syncthreads();
#pragma unroll
    for (int j = 0; j < 4; ++j) {
        int p = p0 + ty + j * 8;
        if (p < 400) out[((size_t)b * 400 + p) * 256 + c0 + tx] = (f16)t[tx][ty + j * 8];
    }
}

// ---------------- pre-pass 2: conv_w [n=256][cin=256][p=81] f32 -> w_t[n][p*256+cin] f16 -
__global__ __launch_bounds__(256) void permute_w(
    const float* __restrict__ cw, f16* __restrict__ w_t)
{
    const int n = blockIdx.x, t = threadIdx.x;
    __shared__ f16 buf[81 * 258];
    const float* src = cw + (size_t)n * 20736;
    for (int i = t; i < 20736; i += 256) {
        int cin = i / 81, p = i - cin * 81;
        buf[p * 258 + cin] = (f16)src[i];
    }
    __syncthreads();
    f16* dst = w_t + (size_t)n * 20736;
    for (int j = t; j < 20736; j += 256) {
        int p = j >> 8, cin = j & 255;
        dst[j] = buf[p * 258 + cin];
    }
}

// ---------------- conv as implicit-im2col MFMA GEMM, 2-phase interleaved pipeline ------
// (UNCHANGED from R2 — measured 61.8 us, MfmaUtil 33.)
#define SPLITK 14
__global__ __launch_bounds__(256, 2) void conv_mfma(
    const f16* __restrict__ in_t,   // [128,20,20,256]
    const f16* __restrict__ w_t,    // [256,20736]
    f16* __restrict__ part)         // [14,4608,256] f16
{
    __shared__ f16 As[3][128 * 32];
    __shared__ f16 Bs[3][256 * 32];
    const int tid = threadIdx.x;
    const int lane = tid & 63, wave = tid >> 6;
    const int wm = wave >> 1, wn = wave & 1;

    const int bid = blockIdx.x + 36 * blockIdx.z;
    const int wgid = (bid & 7) * 63 + (bid >> 3);
    const int m0 = (wgid % 36) * 128;
    const int kz = wgid / 36;

    const int kc0 = kz * 46 + (kz < 4 ? kz : 4);
    const int NT  = (kz < 4) ? 47 : 46;

    int srcA[2], srcB[4];
#pragma unroll
    for (int i = 0; i < 2; ++i) {
        int pairp = i * 32 + (tid >> 3);
        int chunk8 = (tid & 7) ^ (pairp & 7);
        int e = chunk8 >> 2, q4 = chunk8 & 3;
        int m = m0 + pairp * 2 + e;
        int b = m / 36, hw = m - b * 36;
        int ho = hw / 6, wo = hw - ho * 6;
        srcA[i] = ((b * 20 + 2 * ho) * 20 + 2 * wo) * 256 + q4 * 8;
    }
#pragma unroll
    for (int i = 0; i < 4; ++i) {
        int pairp = i * 32 + (tid >> 3);
        int chunk8 = (tid & 7) ^ (pairp & 7);
        int e = chunk8 >> 2, q4 = chunk8 & 3;
        int n = pairp * 2 + e;
        srcB[i] = n * 20736 + q4 * 8;
    }

    const int row = lane & 15, quad = lane >> 4;
    int offA[4], offB[8];
#pragma unroll
    for (int mt = 0; mt < 4; ++mt) {
        int m = wm * 64 + mt * 16 + row;
        int ph8 = (((m & 1) << 2) + quad) ^ ((m >> 1) & 7);
        offA[mt] = (m >> 1) * 64 + ph8 * 8;
    }
#pragma unroll
    for (int nt = 0; nt < 8; ++nt) {
        int n = wn * 128 + nt * 16 + row;
        int ph8 = (((n & 1) << 2) + quad) ^ ((n >> 1) & 7);
        offB[nt] = (n >> 1) * 64 + ph8 * 8;
    }

    f32x4 acc[4][8] = {};

#define KOFFS(T) int kc = kc0 + (T); int pp = kc >> 3, cq = kc & 7;           \
    int kh = pp / 9, kw = pp - kh * 9;                                        \
    int koffA = (kh * 20 + kw) * 256 + cq * 32; int koffB = kc * 32;
#define STAGE1(T, BUF) do { KOFFS(T)                                          \
        gld_lds16(in_t + srcA[0] + koffA, &As[BUF][tid * 8]);                 \
        gld_lds16(in_t + srcA[1] + koffA, &As[BUF][2048 + tid * 8]);          \
        gld_lds16(w_t + srcB[0] + koffB, &Bs[BUF][tid * 8]);                  \
    } while (0)
#define STAGE2(T, BUF) do { KOFFS(T)                                          \
        gld_lds16(w_t + srcB[1] + koffB, &Bs[BUF][2048 + tid * 8]);           \
        gld_lds16(w_t + srcB[2] + koffB, &Bs[BUF][4096 + tid * 8]);           \
        gld_lds16(w_t + srcB[3] + koffB, &Bs[BUF][6144 + tid * 8]);           \
    } while (0)

    STAGE1(0, 0); STAGE2(0, 0);
    STAGE1(1, 1); STAGE2(1, 1);
    asm volatile("s_waitcnt vmcnt(6)" ::: "memory");
    __builtin_amdgcn_s_barrier();

    int buf = 0;
    for (int t = 0; t < NT; ++t) {
        const f16* Ab = &As[buf][0];
        const f16* Bb = &Bs[buf][0];
        int bn = buf + 2; if (bn >= 3) bn -= 3;
        f16x8 af[4], bfr[8];

        // ---------------- phase A: af[0..3], bfr[0..3] -> acc[*][0..3] ----------------
#pragma unroll
        for (int mt = 0; mt < 4; ++mt) af[mt] = *(const f16x8*)(Ab + offA[mt]);
#pragma unroll
        for (int nt = 0; nt < 4; ++nt) bfr[nt] = *(const f16x8*)(Bb + offB[nt]);
        if (t + 2 < NT) STAGE1(t + 2, bn);
        __builtin_amdgcn_s_barrier();
        asm volatile("s_waitcnt lgkmcnt(0)" ::: "memory");
        __builtin_amdgcn_sched_barrier(0);
        __builtin_amdgcn_s_setprio(1);
#pragma unroll
        for (int mt = 0; mt < 4; ++mt)
#pragma unroll
            for (int nt = 0; nt < 4; ++nt)
                acc[mt][nt] = __builtin_amdgcn_mfma_f32_16x16x32_f16(
                    af[mt], bfr[nt], acc[mt][nt], 0, 0, 0);
        __builtin_amdgcn_s_setprio(0);
        __builtin_amdgcn_s_barrier();

        // ---------------- phase B: bfr[4..7] -> acc[*][4..7] --------------------------
#pragma unroll
        for (int nt = 4; nt < 8; ++nt) bfr[nt] = *(const f16x8*)(Bb + offB[nt]);
        if (t + 2 < NT) STAGE2(t + 2, bn);
        if (t + 2 < NT)
            asm volatile("s_waitcnt vmcnt(6)" ::: "memory");
        else if (t + 1 < NT)
            asm volatile("s_waitcnt vmcnt(0)" ::: "memory");
        __builtin_amdgcn_s_barrier();
        asm volatile("s_waitcnt lgkmcnt(0)" ::: "memory");
        __builtin_amdgcn_sched_barrier(0);
        __builtin_amdgcn_s_setprio(1);
#pragma unroll
        for (int mt = 0; mt < 4; ++mt)
#pragma unroll
            for (int nt = 4; nt < 8; ++nt)
                acc[mt][nt] = __builtin_amdgcn_mfma_f32_16x16x32_f16(
                    af[mt], bfr[nt], acc[mt][nt], 0, 0, 0);
        __builtin_amdgcn_s_setprio(0);
        __builtin_amdgcn_s_barrier();

        if (++buf == 3) buf = 0;
    }
#undef STAGE1
#undef STAGE2
#undef KOFFS

    const int col = lane & 15, qr = (lane >> 4) * 4;
    f16* pb = part + (size_t)kz * 4608 * 256;
#pragma unroll
    for (int mt = 0; mt < 4; ++mt)
#pragma unroll
        for (int rg = 0; rg < 4; ++rg) {
            int m = m0 + wm * 64 + mt * 16 + qr + rg;
#pragma unroll
            for (int nt = 0; nt < 8; ++nt) {
                int n = wn * 128 + nt * 16 + col;
                pb[(size_t)m * 256 + n] = (f16)acc[mt][nt][rg];
            }
        }
}

// ---------------- split-K reduce + bias + capsule squash -> x[128,1152,8] ---------------
// R3: 4 outputs/thread, f16x4 (8B) loads, float4 stores. Grid 144 blocks.
__global__ __launch_bounds__(256) void combine_squash(
    const f16* __restrict__ part, const float* __restrict__ bias,
    float* __restrict__ x)
{
    int idx = blockIdx.x * 256 + threadIdx.x;   // over 4608*8
    int m = idx >> 3, g = idx & 7;              // g: group of 4 o's
    int b = m / 36, hw = m - b * 36;
    float val[8][4];
#pragma unroll
    for (int k = 0; k < 8; ++k)
#pragma unroll
        for (int j = 0; j < 4; ++j) val[k][j] = bias[k * 32 + g * 4 + j];
#pragma unroll
    for (int s = 0; s < SPLITK; ++s) {
        const f16* p = part + ((size_t)s * 4608 + m) * 256 + g * 4;
#pragma unroll
        for (int k = 0; k < 8; ++k) {
            f16x4 v = *(const f16x4*)(p + k * 32);
#pragma unroll
            for (int j = 0; j < 4; ++j) val[k][j] += (float)v[j];
        }
    }
#pragma unroll
    for (int j = 0; j < 4; ++j) {
        float sn = 0.f;
#pragma unroll
        for (int k = 0; k < 8; ++k) sn += val[k][j] * val[k][j];
        float scale = sqrtf(sn) / (1.f + sn);
        int r = (g * 4 + j) * 36 + hw;
        float4* xp = (float4*)(x + ((size_t)b * 1152 + r) * 8);
        xp[0] = make_float4(val[0][j] * scale, val[1][j] * scale,
                            val[2][j] * scale, val[3][j] * scale);
        xp[1] = make_float4(val[4][j] * scale, val[5][j] * scale,
                            val[6][j] * scale, val[7][j] * scale);
    }
}

// ---------------- fused routing iteration: recompute pred from x,rw on the fly ----------
// pred[c,b,r,o] = sum_k x[b,r,k]*rw[c,r,k,o]  (f32, never materialized).
// w1==null -> iter0 (logits=0, e=1, no z).  iter2 uses w = w1 + w2 (a2 = pred.(v0+v1)).
// Writes s_out[c,b,16] = sum_r e*pred and z_out[c,b] = sum_r e.
// Grid (10, 32): 4 batches/block, 256 threads: o = tid&15, rr = tid>>4.
__global__ __launch_bounds__(256) void route_fused(
    const float* __restrict__ x,    // [128,1152,8]
    const float* __restrict__ rw,   // [10,1152,8,16]
    const float* __restrict__ w1,   // v0 [10,128,16] or null
    const float* __restrict__ w2,   // v1 or null
    float* __restrict__ s_out,      // [10,128,16]
    float* __restrict__ z_out)      // [10,128] or null
{
    const int c = blockIdx.x, b0 = blockIdx.y * 4;
    const int tid = threadIdx.x;
    const int o = tid & 15, rr = tid >> 4;

    float wv[4] = {0, 0, 0, 0};
    if (w1) {
#pragma unroll
        for (int b = 0; b < 4; ++b) {
            float t = w1[((size_t)c * 128 + b0 + b) * 16 + o];
            if (w2) t += w2[((size_t)c * 128 + b0 + b) * 16 + o];
            wv[b] = t;
        }
    }

    __shared__ float xs[4][64][8];   // 8 KB x-tile
    float sacc[4] = {0, 0, 0, 0};
    float zacc[4] = {0, 0, 0, 0};

    for (int R = 0; R < 1152; R += 64) {
        __syncthreads();
        {   // stage x[b0..b0+4][R..R+64][0..8]: 2048 f32, 8 per thread (2x float4)
            int bb = tid >> 6;
            int off = (tid & 63) * 8;
            const float* src = x + ((size_t)(b0 + bb) * 1152 + R) * 8 + off;
            float4 u0 = ((const float4*)src)[0];
            float4 u1 = ((const float4*)src)[1];
            float* d = &xs[bb][0][0] + off;
            ((float4*)d)[0] = u0; ((float4*)d)[1] = u1;
        }
        __syncthreads();
#pragma unroll
        for (int rt = 0; rt < 4; ++rt) {
            int rl = rt * 16 + rr;
            int r = R + rl;
            const float* wp = rw + (((size_t)c * 1152 + r) * 8) * 16 + o;
            float Wk[8];
#pragma unroll
            for (int k = 0; k < 8; ++k) Wk[k] = wp[k * 16];
#pragma unroll
            for (int b = 0; b < 4; ++b) {
                const float* xv = xs[b][rl];
                float p = xv[0] * Wk[0] + xv[1] * Wk[1] + xv[2] * Wk[2] + xv[3] * Wk[3]
                        + xv[4] * Wk[4] + xv[5] * Wk[5] + xv[6] * Wk[6] + xv[7] * Wk[7];
                if (w1) {
                    float t = p * wv[b];                     // dot over the 16 o-lanes
                    t += __shfl_xor(t, 1);  t += __shfl_xor(t, 2);
                    t += __shfl_xor(t, 4);  t += __shfl_xor(t, 8);
                    float e = __expf(t);
                    sacc[b] += e * p;
                    zacc[b] += e;
                } else {
                    sacc[b] += p;                            // iter0: softmax(0) -> e=1
                }
            }
        }
    }

    __shared__ float red[16][4][16];
    __shared__ float zr[16][4];
    __syncthreads();
#pragma unroll
    for (int b = 0; b < 4; ++b) red[rr][b][o] = sacc[b];
    if (o == 0) {
#pragma unroll
        for (int b = 0; b < 4; ++b) zr[rr][b] = zacc[b];
    }
    __syncthreads();
    if (tid < 64) {
        int b = tid >> 4, oo = tid & 15;
        float t = 0.f;
#pragma unroll
        for (int i = 0; i < 16; ++i) t += red[i][b][oo];
        s_out[((size_t)c * 128 + b0 + b) * 16 + oo] = t;
    } else if (z_out && tid < 68) {
        int b = tid - 64;
        float t = 0.f;
#pragma unroll
        for (int i = 0; i < 16; ++i) t += zr[i][b];
        z_out[(size_t)c * 128 + b0 + b] = t;
    }
}

// ---------------- v = squash(s/z, axis=batch) -> v[10,128,16] (hoisted, once/iter) ------
__global__ __launch_bounds__(128) void v_pre(
    const float* __restrict__ s, const float* __restrict__ z,
    float* __restrict__ v)
{
    const int c = blockIdx.x, b = threadIdx.x;   // 10 blocks, 128 threads
    float sv[16];
    const float* sp = s + ((size_t)c * 128 + b) * 16;
    float zin = z ? 1.f / z[c * 128 + b] : (1.f / 1152.f);
#pragma unroll
    for (int o = 0; o < 16; ++o) sv[o] = sp[o] * zin;
    __shared__ float m[16][129];
#pragma unroll
    for (int o = 0; o < 16; ++o) m[o][b] = sv[o] * sv[o];
    __syncthreads();
    __shared__ float sn[16];
    if (b < 16) {
        float t = 0.f;
        for (int i = 0; i < 128; ++i) t += m[b][i];
        sn[b] = t;
    }
    __syncthreads();
#pragma unroll
    for (int o = 0; o < 16; ++o) {
        float scale = sqrtf(sn[o]) / (1.f + sn[o]);
        v[((size_t)c * 128 + b) * 16 + o] = sv[o] * scale;
    }
}

// ---------------- final: v = squash(s/z, axis=batch) -> out[b,c,o] ----------------------
__global__ __launch_bounds__(128) void squash_final(
    const float* __restrict__ s, const float* __restrict__ z,
    float* __restrict__ out)
{
    const int c = blockIdx.x, b = threadIdx.x;   // 10 blocks, 128 threads
    float sv[16];
    const float* sp = s + ((size_t)c * 128 + b) * 16;
    float zin = 1.f / z[c * 128 + b];
#pragma unroll
    for (int o = 0; o < 16; ++o) sv[o] = sp[o] * zin;
    __shared__ float m[16][129];
#pragma unroll
    for (int o = 0; o < 16; ++o) m[o][b] = sv[o] * sv[o];
    __syncthreads();
    __shared__ float sn[16];
    if (b < 16) {
        float t = 0.f;
        for (int i = 0; i < 128; ++i) t += m[b][i];
        sn[b] = t;
    }
    __syncthreads();
#pragma unroll
    for (int o = 0; o < 16; ++o) {
        float scale = sqrtf(sn[o]) / (1.f + sn[o]);
        out[((size_t)b * 10 + c) * 16 + o] = sv[o] * scale;
    }
}

// ---------------- launch ----------------------------------------------------------------
extern "C" void kernel_launch(void* const* d_in, const int* in_sizes, int n_in,
                              void* d_out, int out_size, void* d_ws, size_t ws_size,
                              hipStream_t stream)
{
    (void)in_sizes; (void)n_in; (void)out_size; (void)ws_size;
    const float* inp = (const float*)d_in[0];
    const float* cw  = (const float*)d_in[1];
    const float* cb  = (const float*)d_in[2];
    const float* rw  = (const float*)d_in[3];
    float* out = (float*)d_out;

    // workspace layout (bytes), total <= 69.9 MB:
    //   [0, 33.0M)        part f16 [14,4608,256]     (conv -> combine)
    //   [33.0M, 59.2M)    in_t f16 (conv-time)  ... after conv, reused as:
    //       x  @33.0M  (4.7 MB) ; sA,zA,sB,zB,v0,v1 after x (~0.34 MB)
    //   [59.2M, 69.9M)    w_t f16 (conv-time only)
    char* ws = (char*)d_ws;
    f16*   part = (f16*)(ws);                       // 33,030,144
    f16*   in_t = (f16*)(ws + 33030144);            // 26,214,400
    f16*   w_t  = (f16*)(ws + 59244544);            // 10,616,832 -> end 69,861,376
    float* x    = (float*)(ws + 33030144);          //  4,718,592 (aliases dead in_t)
    float* sA   = (float*)(ws + 37748736);          //     81,920
    float* zA   = (float*)(ws + 37830656);          //      5,120
    float* sB   = (float*)(ws + 37835776);          //     81,920
    float* zB   = (float*)(ws + 37917696);          //      5,120
    float* v0   = (float*)(ws + 37922816);          //     81,920
    float* v1   = (float*)(ws + 38004736);          //     81,920

    transpose_input<<<dim3(128, 8, 13), dim3(32, 8), 0, stream>>>(inp, in_t);
    permute_w<<<256, 256, 0, stream>>>(cw, w_t);
    conv_mfma<<<dim3(36, 1, SPLITK), 256, 0, stream>>>(in_t, w_t, part);
    combine_squash<<<144, 256, 0, stream>>>(part, cb, x);

    // routing: pred recomputed on the fly each iteration (never materialized)
    route_fused<<<dim3(10, 32), 256, 0, stream>>>(x, rw, nullptr, nullptr, sA, nullptr);
    v_pre<<<10, 128, 0, stream>>>(sA, nullptr, v0);                     // v0 (z0=1152)
    route_fused<<<dim3(10, 32), 256, 0, stream>>>(x, rw, v0, nullptr, sB, zB);   // iter 1
    v_pre<<<10, 128, 0, stream>>>(sB, zB, v1);                          // v1
    route_fused<<<dim3(10, 32), 256, 0, stream>>>(x, rw, v0, v1, sA, zA);        // iter 2
    squash_final<<<10, 128, 0, stream>>>(sA, zA, out);
}

// Round 5
// 310.415 us; speedup vs baseline: 1.3676x; 1.3676x over previous
//
#include <hip/hip_runtime.h>
#include <math.h>

typedef _Float16 f16;
typedef _Float16 f16x4 __attribute__((ext_vector_type(4)));
typedef _Float16 f16x8 __attribute__((ext_vector_type(8)));
typedef float f32x4 __attribute__((ext_vector_type(4)));
typedef float f32x8 __attribute__((ext_vector_type(8)));

#define AS1 __attribute__((address_space(1)))
#define AS3 __attribute__((address_space(3)))

__device__ __forceinline__ void gld_lds16(const f16* g, f16* l) {
#if defined(__has_builtin) && __has_builtin(__builtin_amdgcn_global_load_lds)
    __builtin_amdgcn_global_load_lds((const AS1 void*)g, (AS3 void*)l, 16, 0, 0);
#else
    *(uint4*)l = *(const uint4*)g;
#endif
}

// ---------------- pre-pass 1: input [128,256,20,20] f32 -> [128,20,20,256] f16 ----------
__global__ __launch_bounds__(256) void transpose_input(
    const float* __restrict__ inp, f16* __restrict__ out)
{
    const int b = blockIdx.x, c0 = blockIdx.y * 32, p0 = blockIdx.z * 32;
    const int tx = threadIdx.x, ty = threadIdx.y;   // 32 x 8
    __shared__ float t[32][33];
#pragma unroll
    for (int j = 0; j < 4; ++j) {
        int c = ty + j * 8, p = p0 + tx;
        if (p < 400) t[c][tx] = inp[((size_t)b * 256 + c0 + c) * 400 + p];
    }
    __syncthreads();
#pragma unroll
    for (int j = 0; j < 4; ++j) {
        int p = p0 + ty + j * 8;
        if (p < 400) out[((size_t)b * 400 + p) * 256 + c0 + tx] = (f16)t[tx][ty + j * 8];
    }
}

// ---------------- pre-pass 2: conv_w [n=256][cin=256][p=81] f32 -> w_t[n][p*256+cin] f16 -
__global__ __launch_bounds__(256) void permute_w(
    const float* __restrict__ cw, f16* __restrict__ w_t)
{
    const int n = blockIdx.x, t = threadIdx.x;
    __shared__ f16 buf[81 * 258];
    const float* src = cw + (size_t)n * 20736;
    for (int i = t; i < 20736; i += 256) {
        int cin = i / 81, p = i - cin * 81;
        buf[p * 258 + cin] = (f16)src[i];
    }
    __syncthreads();
    f16* dst = w_t + (size_t)n * 20736;
    for (int j = t; j < 20736; j += 256) {
        int p = j >> 8, cin = j & 255;
        dst[j] = buf[p * 258 + cin];
    }
}

// ---------------- pre-pass 3: rw [10,1152,8,16] f32 -> rw_t [10,1152,16,8] ---------------
// one-time 5.9 MB k<->o transpose so route3 loads W as 2x float4 per (r,o).
__global__ __launch_bounds__(256) void permute_rw(
    const float* __restrict__ rw, float* __restrict__ rw_t)
{
    int g = blockIdx.x * 256 + threadIdx.x;      // over 10*1152*32 = 368640
    int cr = g >> 5, rem = g & 31;               // cr: (c,r) pair
    int o = rem >> 1, h = (rem & 1) * 4;
    const float* src = rw + (size_t)cr * 128 + o;
    float4 v = make_float4(src[(h + 0) * 16], src[(h + 1) * 16],
                           src[(h + 2) * 16], src[(h + 3) * 16]);
    *(float4*)(rw_t + (size_t)cr * 128 + o * 8 + h) = v;
}

// ---------------- conv as implicit-im2col MFMA GEMM, 2-phase interleaved pipeline ------
// (UNCHANGED — measured 61.8 us, MfmaUtil 33.)
#define SPLITK 14
__global__ __launch_bounds__(256, 2) void conv_mfma(
    const f16* __restrict__ in_t,   // [128,20,20,256]
    const f16* __restrict__ w_t,    // [256,20736]
    f16* __restrict__ part)         // [14,4608,256] f16
{
    __shared__ f16 As[3][128 * 32];
    __shared__ f16 Bs[3][256 * 32];
    const int tid = threadIdx.x;
    const int lane = tid & 63, wave = tid >> 6;
    const int wm = wave >> 1, wn = wave & 1;

    const int bid = blockIdx.x + 36 * blockIdx.z;
    const int wgid = (bid & 7) * 63 + (bid >> 3);
    const int m0 = (wgid % 36) * 128;
    const int kz = wgid / 36;

    const int kc0 = kz * 46 + (kz < 4 ? kz : 4);
    const int NT  = (kz < 4) ? 47 : 46;

    int srcA[2], srcB[4];
#pragma unroll
    for (int i = 0; i < 2; ++i) {
        int pairp = i * 32 + (tid >> 3);
        int chunk8 = (tid & 7) ^ (pairp & 7);
        int e = chunk8 >> 2, q4 = chunk8 & 3;
        int m = m0 + pairp * 2 + e;
        int b = m / 36, hw = m - b * 36;
        int ho = hw / 6, wo = hw - ho * 6;
        srcA[i] = ((b * 20 + 2 * ho) * 20 + 2 * wo) * 256 + q4 * 8;
    }
#pragma unroll
    for (int i = 0; i < 4; ++i) {
        int pairp = i * 32 + (tid >> 3);
        int chunk8 = (tid & 7) ^ (pairp & 7);
        int e = chunk8 >> 2, q4 = chunk8 & 3;
        int n = pairp * 2 + e;
        srcB[i] = n * 20736 + q4 * 8;
    }

    const int row = lane & 15, quad = lane >> 4;
    int offA[4], offB[8];
#pragma unroll
    for (int mt = 0; mt < 4; ++mt) {
        int m = wm * 64 + mt * 16 + row;
        int ph8 = (((m & 1) << 2) + quad) ^ ((m >> 1) & 7);
        offA[mt] = (m >> 1) * 64 + ph8 * 8;
    }
#pragma unroll
    for (int nt = 0; nt < 8; ++nt) {
        int n = wn * 128 + nt * 16 + row;
        int ph8 = (((n & 1) << 2) + quad) ^ ((n >> 1) & 7);
        offB[nt] = (n >> 1) * 64 + ph8 * 8;
    }

    f32x4 acc[4][8] = {};

#define KOFFS(T) int kc = kc0 + (T); int pp = kc >> 3, cq = kc & 7;           \
    int kh = pp / 9, kw = pp - kh * 9;                                        \
    int koffA = (kh * 20 + kw) * 256 + cq * 32; int koffB = kc * 32;
#define STAGE1(T, BUF) do { KOFFS(T)                                          \
        gld_lds16(in_t + srcA[0] + koffA, &As[BUF][tid * 8]);                 \
        gld_lds16(in_t + srcA[1] + koffA, &As[BUF][2048 + tid * 8]);          \
        gld_lds16(w_t + srcB[0] + koffB, &Bs[BUF][tid * 8]);                  \
    } while (0)
#define STAGE2(T, BUF) do { KOFFS(T)                                          \
        gld_lds16(w_t + srcB[1] + koffB, &Bs[BUF][2048 + tid * 8]);           \
        gld_lds16(w_t + srcB[2] + koffB, &Bs[BUF][4096 + tid * 8]);           \
        gld_lds16(w_t + srcB[3] + koffB, &Bs[BUF][6144 + tid * 8]);           \
    } while (0)

    STAGE1(0, 0); STAGE2(0, 0);
    STAGE1(1, 1); STAGE2(1, 1);
    asm volatile("s_waitcnt vmcnt(6)" ::: "memory");
    __builtin_amdgcn_s_barrier();

    int buf = 0;
    for (int t = 0; t < NT; ++t) {
        const f16* Ab = &As[buf][0];
        const f16* Bb = &Bs[buf][0];
        int bn = buf + 2; if (bn >= 3) bn -= 3;
        f16x8 af[4], bfr[8];

        // ---------------- phase A: af[0..3], bfr[0..3] -> acc[*][0..3] ----------------
#pragma unroll
        for (int mt = 0; mt < 4; ++mt) af[mt] = *(const f16x8*)(Ab + offA[mt]);
#pragma unroll
        for (int nt = 0; nt < 4; ++nt) bfr[nt] = *(const f16x8*)(Bb + offB[nt]);
        if (t + 2 < NT) STAGE1(t + 2, bn);
        __builtin_amdgcn_s_barrier();
        asm volatile("s_waitcnt lgkmcnt(0)" ::: "memory");
        __builtin_amdgcn_sched_barrier(0);
        __builtin_amdgcn_s_setprio(1);
#pragma unroll
        for (int mt = 0; mt < 4; ++mt)
#pragma unroll
            for (int nt = 0; nt < 4; ++nt)
                acc[mt][nt] = __builtin_amdgcn_mfma_f32_16x16x32_f16(
                    af[mt], bfr[nt], acc[mt][nt], 0, 0, 0);
        __builtin_amdgcn_s_setprio(0);
        __builtin_amdgcn_s_barrier();

        // ---------------- phase B: bfr[4..7] -> acc[*][4..7] --------------------------
#pragma unroll
        for (int nt = 4; nt < 8; ++nt) bfr[nt] = *(const f16x8*)(Bb + offB[nt]);
        if (t + 2 < NT) STAGE2(t + 2, bn);
        if (t + 2 < NT)
            asm volatile("s_waitcnt vmcnt(6)" ::: "memory");
        else if (t + 1 < NT)
            asm volatile("s_waitcnt vmcnt(0)" ::: "memory");
        __builtin_amdgcn_s_barrier();
        asm volatile("s_waitcnt lgkmcnt(0)" ::: "memory");
        __builtin_amdgcn_sched_barrier(0);
        __builtin_amdgcn_s_setprio(1);
#pragma unroll
        for (int mt = 0; mt < 4; ++mt)
#pragma unroll
            for (int nt = 4; nt < 8; ++nt)
                acc[mt][nt] = __builtin_amdgcn_mfma_f32_16x16x32_f16(
                    af[mt], bfr[nt], acc[mt][nt], 0, 0, 0);
        __builtin_amdgcn_s_setprio(0);
        __builtin_amdgcn_s_barrier();

        if (++buf == 3) buf = 0;
    }
#undef STAGE1
#undef STAGE2
#undef KOFFS

    const int col = lane & 15, qr = (lane >> 4) * 4;
    f16* pb = part + (size_t)kz * 4608 * 256;
#pragma unroll
    for (int mt = 0; mt < 4; ++mt)
#pragma unroll
        for (int rg = 0; rg < 4; ++rg) {
            int m = m0 + wm * 64 + mt * 16 + qr + rg;
#pragma unroll
            for (int nt = 0; nt < 8; ++nt) {
                int n = wn * 128 + nt * 16 + col;
                pb[(size_t)m * 256 + n] = (f16)acc[mt][nt][rg];
            }
        }
}

// ---------------- split-K reduce + bias + capsule squash -> x[128,1152,8] ---------------
__global__ __launch_bounds__(256) void combine_squash(
    const f16* __restrict__ part, const float* __restrict__ bias,
    float* __restrict__ x)
{
    int idx = blockIdx.x * 256 + threadIdx.x;   // over 4608*8
    int m = idx >> 3, g = idx & 7;              // g: group of 4 o's
    int b = m / 36, hw = m - b * 36;
    float val[8][4];
#pragma unroll
    for (int k = 0; k < 8; ++k)
#pragma unroll
        for (int j = 0; j < 4; ++j) val[k][j] = bias[k * 32 + g * 4 + j];
#pragma unroll
    for (int s = 0; s < SPLITK; ++s) {
        const f16* p = part + ((size_t)s * 4608 + m) * 256 + g * 4;
#pragma unroll
        for (int k = 0; k < 8; ++k) {
            f16x4 v = *(const f16x4*)(p + k * 32);
#pragma unroll
            for (int j = 0; j < 4; ++j) val[k][j] += (float)v[j];
        }
    }
#pragma unroll
    for (int j = 0; j < 4; ++j) {
        float sn = 0.f;
#pragma unroll
        for (int k = 0; k < 8; ++k) sn += val[k][j] * val[k][j];
        float scale = sqrtf(sn) / (1.f + sn);
        int r = (g * 4 + j) * 36 + hw;
        float4* xp = (float4*)(x + ((size_t)b * 1152 + r) * 8);
        xp[0] = make_float4(val[0][j] * scale, val[1][j] * scale,
                            val[2][j] * scale, val[3][j] * scale);
        xp[1] = make_float4(val[4][j] * scale, val[5][j] * scale,
                            val[6][j] * scale, val[7][j] * scale);
    }
}

// ---------------- fused routing iteration, r-split + atomic reduce ---------------------
// pred recomputed on the fly (f32, never materialized). w1==null -> iter0 (e=1).
// iter2: w = w1 + w2 (telescoped logits a2 = pred.(v0+v1)).
// Grid (10, 32, 4): block = (c, 4 batches, 288 routes). 256 thr: o=tid&15, rr=tid>>4.
// s_out/z_out accumulated via atomicAdd (pre-zeroed).
__global__ __launch_bounds__(256) void route3(
    const float* __restrict__ x,     // [128,1152,8]
    const float* __restrict__ rwt,   // [10,1152,16,8]
    const float* __restrict__ w1,    // v0 [10,128,16] or null
    const float* __restrict__ w2,    // v1 or null
    float* __restrict__ s_out,       // [10,128,16]  (pre-zeroed)
    float* __restrict__ z_out)       // [10,128] or null (pre-zeroed)
{
    const int c = blockIdx.x, b0 = blockIdx.y * 4, rbase = blockIdx.z * 288;
    const int tid = threadIdx.x;
    const int o = tid & 15, rr = tid >> 4;

    float wv[4] = {0, 0, 0, 0};
    if (w1) {
#pragma unroll
        for (int b = 0; b < 4; ++b) {
            float t = w1[((size_t)c * 128 + b0 + b) * 16 + o];
            if (w2) t += w2[((size_t)c * 128 + b0 + b) * 16 + o];
            wv[b] = t;
        }
    }

    float sacc[4] = {0, 0, 0, 0};
    float zacc[4] = {0, 0, 0, 0};

    for (int rt = 0; rt < 18; ++rt) {
        const int r = rbase + rt * 16 + rr;
        const float* wp = rwt + ((size_t)(c * 1152 + r) * 16 + o) * 8;
        float4 wa = ((const float4*)wp)[0];
        float4 wb = ((const float4*)wp)[1];
#pragma unroll
        for (int b = 0; b < 4; ++b) {
            const float* xp = x + ((size_t)(b0 + b) * 1152 + r) * 8;
            float4 xa = ((const float4*)xp)[0];
            float4 xb = ((const float4*)xp)[1];
            float p = xa.x * wa.x + xa.y * wa.y + xa.z * wa.z + xa.w * wa.w
                    + xb.x * wb.x + xb.y * wb.y + xb.z * wb.z + xb.w * wb.w;
            if (w1) {
                float t = p * wv[b];                 // dot over the 16 o-lanes
                t += __shfl_xor(t, 1);  t += __shfl_xor(t, 2);
                t += __shfl_xor(t, 4);  t += __shfl_xor(t, 8);
                float e = __expf(t);
                sacc[b] += e * p;
                zacc[b] += e;
            } else {
                sacc[b] += p;                        // iter0: softmax(0) -> e=1
            }
        }
    }

    __shared__ float red[16][4][17];
    __shared__ float zr[16][4];
#pragma unroll
    for (int b = 0; b < 4; ++b) red[rr][b][o] = sacc[b];
    if (o == 0) {
#pragma unroll
        for (int b = 0; b < 4; ++b) zr[rr][b] = zacc[b];
    }
    __syncthreads();
    if (tid < 64) {
        int b = tid >> 4, oo = tid & 15;
        float t = 0.f;
#pragma unroll
        for (int i = 0; i < 16; ++i) t += red[i][b][oo];
        atomicAdd(&s_out[((size_t)c * 128 + b0 + b) * 16 + oo], t);
    } else if (z_out && tid < 68) {
        int b = tid - 64;
        float t = 0.f;
#pragma unroll
        for (int i = 0; i < 16; ++i) t += zr[i][b];
        atomicAdd(&z_out[(size_t)c * 128 + b0 + b], t);
    }
}

// ---------------- v = squash(s/z, axis=batch) -> v[10,128,16] (hoisted, once/iter) ------
__global__ __launch_bounds__(128) void v_pre(
    const float* __restrict__ s, const float* __restrict__ z,
    float* __restrict__ v)
{
    const int c = blockIdx.x, b = threadIdx.x;   // 10 blocks, 128 threads
    float sv[16];
    const float* sp = s + ((size_t)c * 128 + b) * 16;
    float zin = z ? 1.f / z[c * 128 + b] : (1.f / 1152.f);
#pragma unroll
    for (int o = 0; o < 16; ++o) sv[o] = sp[o] * zin;
    __shared__ float m[16][129];
#pragma unroll
    for (int o = 0; o < 16; ++o) m[o][b] = sv[o] * sv[o];
    __syncthreads();
    __shared__ float sn[16];
    if (b < 16) {
        float t = 0.f;
        for (int i = 0; i < 128; ++i) t += m[b][i];
        sn[b] = t;
    }
    __syncthreads();
#pragma unroll
    for (int o = 0; o < 16; ++o) {
        float scale = sqrtf(sn[o]) / (1.f + sn[o]);
        v[((size_t)c * 128 + b) * 16 + o] = sv[o] * scale;
    }
}

// ---------------- final: v = squash(s/z, axis=batch) -> out[b,c,o] ----------------------
__global__ __launch_bounds__(128) void squash_final(
    const float* __restrict__ s, const float* __restrict__ z,
    float* __restrict__ out)
{
    const int c = blockIdx.x, b = threadIdx.x;   // 10 blocks, 128 threads
    float sv[16];
    const float* sp = s + ((size_t)c * 128 + b) * 16;
    float zin = 1.f / z[c * 128 + b];
#pragma unroll
    for (int o = 0; o < 16; ++o) sv[o] = sp[o] * zin;
    __shared__ float m[16][129];
#pragma unroll
    for (int o = 0; o < 16; ++o) m[o][b] = sv[o] * sv[o];
    __syncthreads();
    __shared__ float sn[16];
    if (b < 16) {
        float t = 0.f;
        for (int i = 0; i < 128; ++i) t += m[b][i];
        sn[b] = t;
    }
    __syncthreads();
#pragma unroll
    for (int o = 0; o < 16; ++o) {
        float scale = sqrtf(sn[o]) / (1.f + sn[o]);
        out[((size_t)b * 10 + c) * 16 + o] = sv[o] * scale;
    }
}

// ---------------- launch ----------------------------------------------------------------
extern "C" void kernel_launch(void* const* d_in, const int* in_sizes, int n_in,
                              void* d_out, int out_size, void* d_ws, size_t ws_size,
                              hipStream_t stream)
{
    (void)in_sizes; (void)n_in; (void)out_size; (void)ws_size;
    const float* inp = (const float*)d_in[0];
    const float* cw  = (const float*)d_in[1];
    const float* cb  = (const float*)d_in[2];
    const float* rw  = (const float*)d_in[3];
    float* out = (float*)d_out;

    // workspace layout (bytes), total ~76.2 MB:
    //   [0, 33.0M)        part f16 [14,4608,256]   (conv -> combine)
    //   [33.0M, 59.2M)    in_t f16 (conv-time); x f32 aliases it after conv (4.7 MB)
    //   [59.2M, 69.9M)    w_t f16 (conv-time only)
    //   [69.9M, 75.8M)    rw_t f32 [10,1152,16,8]
    //   [75.8M, 76.2M)    s0,s1,s2 (3x81920) z1,z2 (2x5120) v0,v1 (2x81920)
    char* ws = (char*)d_ws;
    f16*   part = (f16*)(ws);                       // 33,030,144
    f16*   in_t = (f16*)(ws + 33030144);            // 26,214,400
    f16*   w_t  = (f16*)(ws + 59244544);            // 10,616,832 -> 69,861,376
    float* x    = (float*)(ws + 33030144);          //  4,718,592 (aliases dead in_t)
    float* rwt  = (float*)(ws + 69861376);          //  5,898,240 -> 75,759,616
    float* s0   = (float*)(ws + 75759616);          //     81,920
    float* s1   = (float*)(ws + 75841536);          //     81,920
    float* s2   = (float*)(ws + 75923456);          //     81,920
    float* z1   = (float*)(ws + 76005376);          //      5,120
    float* z2   = (float*)(ws + 76010496);          //      5,120
    float* v0   = (float*)(ws + 76015616);          //     81,920
    float* v1   = (float*)(ws + 76097536);          //     81,920 -> 76,179,456

    // zero all routing accumulators (s0..s2,z1,z2 contiguous = 256 KB)
    hipMemsetAsync(s0, 0, 3 * 81920 + 2 * 5120, stream);

    transpose_input<<<dim3(128, 8, 13), dim3(32, 8), 0, stream>>>(inp, in_t);
    permute_w<<<256, 256, 0, stream>>>(cw, w_t);
    permute_rw<<<1440, 256, 0, stream>>>(rw, rwt);
    conv_mfma<<<dim3(36, 1, SPLITK), 256, 0, stream>>>(in_t, w_t, part);
    combine_squash<<<144, 256, 0, stream>>>(part, cb, x);

    // routing: pred recomputed on the fly each iteration (never materialized)
    route3<<<dim3(10, 32, 4), 256, 0, stream>>>(x, rwt, nullptr, nullptr, s0, nullptr);
    v_pre<<<10, 128, 0, stream>>>(s0, nullptr, v0);                      // v0 (z0=1152)
    route3<<<dim3(10, 32, 4), 256, 0, stream>>>(x, rwt, v0, nullptr, s1, z1);   // iter 1
    v_pre<<<10, 128, 0, stream>>>(s1, z1, v1);                           // v1
    route3<<<dim3(10, 32, 4), 256, 0, stream>>>(x, rwt, v0, v1, s2, z2);        // iter 2
    squash_final<<<10, 128, 0, stream>>>(s2, z2, out);
}

// Round 6
// 269.260 us; speedup vs baseline: 1.5766x; 1.1528x over previous
//
#include <hip/hip_runtime.h>
#include <math.h>

typedef _Float16 f16;
typedef _Float16 f16x4 __attribute__((ext_vector_type(4)));
typedef _Float16 f16x8 __attribute__((ext_vector_type(8)));
typedef float f32x4 __attribute__((ext_vector_type(4)));
typedef float f32x8 __attribute__((ext_vector_type(8)));

#define AS1 __attribute__((address_space(1)))
#define AS3 __attribute__((address_space(3)))

__device__ __forceinline__ void gld_lds16(const f16* g, f16* l) {
#if defined(__has_builtin) && __has_builtin(__builtin_amdgcn_global_load_lds)
    __builtin_amdgcn_global_load_lds((const AS1 void*)g, (AS3 void*)l, 16, 0, 0);
#else
    *(uint4*)l = *(const uint4*)g;
#endif
}

// ---------------- pre-pass 1: input [128,256,20,20] f32 -> [128,20,20,256] f16 ----------
__global__ __launch_bounds__(256) void transpose_input(
    const float* __restrict__ inp, f16* __restrict__ out)
{
    const int b = blockIdx.x, c0 = blockIdx.y * 32, p0 = blockIdx.z * 32;
    const int tx = threadIdx.x, ty = threadIdx.y;   // 32 x 8
    __shared__ float t[32][33];
#pragma unroll
    for (int j = 0; j < 4; ++j) {
        int c = ty + j * 8, p = p0 + tx;
        if (p < 400) t[c][tx] = inp[((size_t)b * 256 + c0 + c) * 400 + p];
    }
    __syncthreads();
#pragma unroll
    for (int j = 0; j < 4; ++j) {
        int p = p0 + ty + j * 8;
        if (p < 400) out[((size_t)b * 400 + p) * 256 + c0 + tx] = (f16)t[tx][ty + j * 8];
    }
}

// ---------------- pre-pass 2: conv_w [n=256][cin=256][p=81] f32 -> w_t[n][p*256+cin] f16 -
__global__ __launch_bounds__(256) void permute_w(
    const float* __restrict__ cw, f16* __restrict__ w_t)
{
    const int n = blockIdx.x, t = threadIdx.x;
    __shared__ f16 buf[81 * 258];
    const float* src = cw + (size_t)n * 20736;
    for (int i = t; i < 20736; i += 256) {
        int cin = i / 81, p = i - cin * 81;
        buf[p * 258 + cin] = (f16)src[i];
    }
    __syncthreads();
    f16* dst = w_t + (size_t)n * 20736;
    for (int j = t; j < 20736; j += 256) {
        int p = j >> 8, cin = j & 255;
        dst[j] = buf[p * 258 + cin];
    }
}

// ---------------- pre-pass 3: rw [10,1152,8,16] f32 -> rwh [10,1152,16,8] f16 ------------
__global__ __launch_bounds__(256) void permute_rw(
    const float* __restrict__ rw, f16* __restrict__ rwh)
{
    int g = blockIdx.x * 256 + threadIdx.x;      // over 10*1152*32 = 368640
    int cr = g >> 5, rem = g & 31;               // cr: (c,r) pair
    int o = rem >> 1, h = (rem & 1) * 4;
    const float* src = rw + (size_t)cr * 128 + o;
    f16x4 v;
#pragma unroll
    for (int j = 0; j < 4; ++j) v[j] = (f16)src[(h + j) * 16];
    *(f16x4*)(rwh + (size_t)cr * 128 + o * 8 + h) = v;
}

// ---------------- conv as implicit-im2col MFMA GEMM, 2-phase interleaved pipeline ------
// (UNCHANGED — measured 60.4 us, MfmaUtil 33.)
#define SPLITK 14
__global__ __launch_bounds__(256, 2) void conv_mfma(
    const f16* __restrict__ in_t,   // [128,20,20,256]
    const f16* __restrict__ w_t,    // [256,20736]
    f16* __restrict__ part)         // [14,4608,256] f16
{
    __shared__ f16 As[3][128 * 32];
    __shared__ f16 Bs[3][256 * 32];
    const int tid = threadIdx.x;
    const int lane = tid & 63, wave = tid >> 6;
    const int wm = wave >> 1, wn = wave & 1;

    const int bid = blockIdx.x + 36 * blockIdx.z;
    const int wgid = (bid & 7) * 63 + (bid >> 3);
    const int m0 = (wgid % 36) * 128;
    const int kz = wgid / 36;

    const int kc0 = kz * 46 + (kz < 4 ? kz : 4);
    const int NT  = (kz < 4) ? 47 : 46;

    int srcA[2], srcB[4];
#pragma unroll
    for (int i = 0; i < 2; ++i) {
        int pairp = i * 32 + (tid >> 3);
        int chunk8 = (tid & 7) ^ (pairp & 7);
        int e = chunk8 >> 2, q4 = chunk8 & 3;
        int m = m0 + pairp * 2 + e;
        int b = m / 36, hw = m - b * 36;
        int ho = hw / 6, wo = hw - ho * 6;
        srcA[i] = ((b * 20 + 2 * ho) * 20 + 2 * wo) * 256 + q4 * 8;
    }
#pragma unroll
    for (int i = 0; i < 4; ++i) {
        int pairp = i * 32 + (tid >> 3);
        int chunk8 = (tid & 7) ^ (pairp & 7);
        int e = chunk8 >> 2, q4 = chunk8 & 3;
        int n = pairp * 2 + e;
        srcB[i] = n * 20736 + q4 * 8;
    }

    const int row = lane & 15, quad = lane >> 4;
    int offA[4], offB[8];
#pragma unroll
    for (int mt = 0; mt < 4; ++mt) {
        int m = wm * 64 + mt * 16 + row;
        int ph8 = (((m & 1) << 2) + quad) ^ ((m >> 1) & 7);
        offA[mt] = (m >> 1) * 64 + ph8 * 8;
    }
#pragma unroll
    for (int nt = 0; nt < 8; ++nt) {
        int n = wn * 128 + nt * 16 + row;
        int ph8 = (((n & 1) << 2) + quad) ^ ((n >> 1) & 7);
        offB[nt] = (n >> 1) * 64 + ph8 * 8;
    }

    f32x4 acc[4][8] = {};

#define KOFFS(T) int kc = kc0 + (T); int pp = kc >> 3, cq = kc & 7;           \
    int kh = pp / 9, kw = pp - kh * 9;                                        \
    int koffA = (kh * 20 + kw) * 256 + cq * 32; int koffB = kc * 32;
#define STAGE1(T, BUF) do { KOFFS(T)                                          \
        gld_lds16(in_t + srcA[0] + koffA, &As[BUF][tid * 8]);                 \
        gld_lds16(in_t + srcA[1] + koffA, &As[BUF][2048 + tid * 8]);          \
        gld_lds16(w_t + srcB[0] + koffB, &Bs[BUF][tid * 8]);                  \
    } while (0)
#define STAGE2(T, BUF) do { KOFFS(T)                                          \
        gld_lds16(w_t + srcB[1] + koffB, &Bs[BUF][2048 + tid * 8]);           \
        gld_lds16(w_t + srcB[2] + koffB, &Bs[BUF][4096 + tid * 8]);           \
        gld_lds16(w_t + srcB[3] + koffB, &Bs[BUF][6144 + tid * 8]);           \
    } while (0)

    STAGE1(0, 0); STAGE2(0, 0);
    STAGE1(1, 1); STAGE2(1, 1);
    asm volatile("s_waitcnt vmcnt(6)" ::: "memory");
    __builtin_amdgcn_s_barrier();

    int buf = 0;
    for (int t = 0; t < NT; ++t) {
        const f16* Ab = &As[buf][0];
        const f16* Bb = &Bs[buf][0];
        int bn = buf + 2; if (bn >= 3) bn -= 3;
        f16x8 af[4], bfr[8];

        // ---------------- phase A: af[0..3], bfr[0..3] -> acc[*][0..3] ----------------
#pragma unroll
        for (int mt = 0; mt < 4; ++mt) af[mt] = *(const f16x8*)(Ab + offA[mt]);
#pragma unroll
        for (int nt = 0; nt < 4; ++nt) bfr[nt] = *(const f16x8*)(Bb + offB[nt]);
        if (t + 2 < NT) STAGE1(t + 2, bn);
        __builtin_amdgcn_s_barrier();
        asm volatile("s_waitcnt lgkmcnt(0)" ::: "memory");
        __builtin_amdgcn_sched_barrier(0);
        __builtin_amdgcn_s_setprio(1);
#pragma unroll
        for (int mt = 0; mt < 4; ++mt)
#pragma unroll
            for (int nt = 0; nt < 4; ++nt)
                acc[mt][nt] = __builtin_amdgcn_mfma_f32_16x16x32_f16(
                    af[mt], bfr[nt], acc[mt][nt], 0, 0, 0);
        __builtin_amdgcn_s_setprio(0);
        __builtin_amdgcn_s_barrier();

        // ---------------- phase B: bfr[4..7] -> acc[*][4..7] --------------------------
#pragma unroll
        for (int nt = 4; nt < 8; ++nt) bfr[nt] = *(const f16x8*)(Bb + offB[nt]);
        if (t + 2 < NT) STAGE2(t + 2, bn);
        if (t + 2 < NT)
            asm volatile("s_waitcnt vmcnt(6)" ::: "memory");
        else if (t + 1 < NT)
            asm volatile("s_waitcnt vmcnt(0)" ::: "memory");
        __builtin_amdgcn_s_barrier();
        asm volatile("s_waitcnt lgkmcnt(0)" ::: "memory");
        __builtin_amdgcn_sched_barrier(0);
        __builtin_amdgcn_s_setprio(1);
#pragma unroll
        for (int mt = 0; mt < 4; ++mt)
#pragma unroll
            for (int nt = 4; nt < 8; ++nt)
                acc[mt][nt] = __builtin_amdgcn_mfma_f32_16x16x32_f16(
                    af[mt], bfr[nt], acc[mt][nt], 0, 0, 0);
        __builtin_amdgcn_s_setprio(0);
        __builtin_amdgcn_s_barrier();

        if (++buf == 3) buf = 0;
    }
#undef STAGE1
#undef STAGE2
#undef KOFFS

    const int col = lane & 15, qr = (lane >> 4) * 4;
    f16* pb = part + (size_t)kz * 4608 * 256;
#pragma unroll
    for (int mt = 0; mt < 4; ++mt)
#pragma unroll
        for (int rg = 0; rg < 4; ++rg) {
            int m = m0 + wm * 64 + mt * 16 + qr + rg;
#pragma unroll
            for (int nt = 0; nt < 8; ++nt) {
                int n = wn * 128 + nt * 16 + col;
                pb[(size_t)m * 256 + n] = (f16)acc[mt][nt][rg];
            }
        }
}

// ---------------- split-K reduce + bias + capsule squash -> xh[128,1152,8] f16 ----------
__global__ __launch_bounds__(256) void combine_squash(
    const f16* __restrict__ part, const float* __restrict__ bias,
    f16* __restrict__ xh)
{
    int idx = blockIdx.x * 256 + threadIdx.x;   // over 4608*8
    int m = idx >> 3, g = idx & 7;              // g: group of 4 o's
    int b = m / 36, hw = m - b * 36;
    float val[8][4];
#pragma unroll
    for (int k = 0; k < 8; ++k)
#pragma unroll
        for (int j = 0; j < 4; ++j) val[k][j] = bias[k * 32 + g * 4 + j];
#pragma unroll
    for (int s = 0; s < SPLITK; ++s) {
        const f16* p = part + ((size_t)s * 4608 + m) * 256 + g * 4;
#pragma unroll
        for (int k = 0; k < 8; ++k) {
            f16x4 v = *(const f16x4*)(p + k * 32);
#pragma unroll
            for (int j = 0; j < 4; ++j) val[k][j] += (float)v[j];
        }
    }
#pragma unroll
    for (int j = 0; j < 4; ++j) {
        float sn = 0.f;
#pragma unroll
        for (int k = 0; k < 8; ++k) sn += val[k][j] * val[k][j];
        float scale = sqrtf(sn) / (1.f + sn);
        int r = (g * 4 + j) * 36 + hw;
        f16x8 hv;
#pragma unroll
        for (int k = 0; k < 8; ++k) hv[k] = (f16)(val[k][j] * scale);
        *(f16x8*)(xh + ((size_t)b * 1152 + r) * 8) = hv;
    }
}

// ---------------- fused routing iteration (v-compute folded into preamble) --------------
// pred recomputed on the fly from f16 xh/rwh (f32 accumulate, never materialized).
// wv = v_a(+v_b) computed in-block from (sa,za)/(sb,zb); sa==null -> iter0 (e=1).
// Grid 1280 blocks / 256 thr. XCD chunk swizzle: logical lid groups the 32 blocks that
// share a (c, r-slice) rwh panel into one XCD's contiguous chunk (panel stays L2-hot).
// s_out/z_out accumulated via atomicAdd (pre-zeroed).
__global__ __launch_bounds__(256) void route_it(
    const f16* __restrict__ xh,     // [128,1152,8] f16
    const f16* __restrict__ rwh,    // [10,1152,16,8] f16
    const float* __restrict__ sa, const float* __restrict__ za,  // v_a (za null -> 1/1152)
    const float* __restrict__ sb, const float* __restrict__ zb,  // v_b or null
    float* __restrict__ s_out,      // [10,128,16]  (pre-zeroed)
    float* __restrict__ z_out)      // [10,128] or null (pre-zeroed)
{
    const int bid = blockIdx.x;
    const int lid = (bid & 7) * 160 + (bid >> 3);      // 1280 = 8 XCDs x 160, bijective
    const int bq = lid & 31, gt = lid >> 5;            // 32 consecutive lid share (c,rz)
    const int c = gt % 10, rz = gt / 10;
    const int b0 = bq * 4, rbase = rz * 288;
    const int tid = threadIdx.x;
    const int o = tid & 15, seg = tid >> 4;

    __shared__ float lred[16][17];
    __shared__ float lsn[16];

    float wv[4] = {0.f, 0.f, 0.f, 0.f};
    const bool have_w = (sa != nullptr);

#define VFOLD(S, Z) do {                                                      \
        float part_ = 0.f;                                                    \
        _Pragma("unroll")                                                     \
        for (int j = 0; j < 8; ++j) {                                         \
            int bb = seg * 8 + j;                                             \
            float zin = (Z) ? 1.f / (Z)[c * 128 + bb] : (1.f / 1152.f);       \
            float q = (S)[((size_t)c * 128 + bb) * 16 + o] * zin;             \
            part_ += q * q;                                                   \
        }                                                                     \
        lred[seg][o] = part_;                                                 \
        __syncthreads();                                                      \
        if (tid < 16) {                                                       \
            float t_ = 0.f;                                                   \
            _Pragma("unroll")                                                 \
            for (int i = 0; i < 16; ++i) t_ += lred[i][tid];                  \
            lsn[tid] = t_;                                                    \
        }                                                                     \
        __syncthreads();                                                      \
        {                                                                     \
            float sn_ = lsn[o];                                               \
            float sc_ = sqrtf(sn_) / (1.f + sn_);                             \
            _Pragma("unroll")                                                 \
            for (int b = 0; b < 4; ++b) {                                     \
                int bb = b0 + b;                                              \
                float zin = (Z) ? 1.f / (Z)[c * 128 + bb] : (1.f / 1152.f);   \
                wv[b] += (S)[((size_t)c * 128 + bb) * 16 + o] * zin * sc_;    \
            }                                                                 \
        }                                                                     \
        __syncthreads();                                                      \
    } while (0)

    if (sa) VFOLD(sa, za);
    if (sb) VFOLD(sb, zb);
#undef VFOLD

    float sacc[4] = {0.f, 0.f, 0.f, 0.f};
    float zacc[4] = {0.f, 0.f, 0.f, 0.f};

    // main loop: 18 r-steps of 16, unrolled x2; all 10 independent 16B loads issued
    // before any compute so HBM/L2 latency overlaps (the R5 VGPR=24 serial-chain fix).
    for (int rt = 0; rt < 18; rt += 2) {
        const int r0 = rbase + rt * 16 + seg;
        const int r1 = r0 + 16;
        f16x8 wf0 = *(const f16x8*)(rwh + ((size_t)(c * 1152 + r0) * 16 + o) * 8);
        f16x8 wf1 = *(const f16x8*)(rwh + ((size_t)(c * 1152 + r1) * 16 + o) * 8);
        f16x8 xf0[4], xf1[4];
#pragma unroll
        for (int b = 0; b < 4; ++b) {
            xf0[b] = *(const f16x8*)(xh + ((size_t)(b0 + b) * 1152 + r0) * 8);
            xf1[b] = *(const f16x8*)(xh + ((size_t)(b0 + b) * 1152 + r1) * 8);
        }
        f32x8 w0 = __builtin_convertvector(wf0, f32x8);
        f32x8 w1 = __builtin_convertvector(wf1, f32x8);
#pragma unroll
        for (int b = 0; b < 4; ++b) {
            f32x8 xa = __builtin_convertvector(xf0[b], f32x8);
            f32x8 xc = __builtin_convertvector(xf1[b], f32x8);
            float p0 = xa[0]*w0[0] + xa[1]*w0[1] + xa[2]*w0[2] + xa[3]*w0[3]
                     + xa[4]*w0[4] + xa[5]*w0[5] + xa[6]*w0[6] + xa[7]*w0[7];
            float p1 = xc[0]*w1[0] + xc[1]*w1[1] + xc[2]*w1[2] + xc[3]*w1[3]
                     + xc[4]*w1[4] + xc[5]*w1[5] + xc[6]*w1[6] + xc[7]*w1[7];
            if (have_w) {
                float t0 = p0 * wv[b], t1 = p1 * wv[b];
                t0 += __shfl_xor(t0, 1); t1 += __shfl_xor(t1, 1);
                t0 += __shfl_xor(t0, 2); t1 += __shfl_xor(t1, 2);
                t0 += __shfl_xor(t0, 4); t1 += __shfl_xor(t1, 4);
                t0 += __shfl_xor(t0, 8); t1 += __shfl_xor(t1, 8);
                float e0 = __expf(t0), e1 = __expf(t1);
                sacc[b] += e0 * p0 + e1 * p1;
                zacc[b] += e0 + e1;
            } else {
                sacc[b] += p0 + p1;                  // iter0: softmax(0) -> e=1
            }
        }
    }

    __shared__ float red[16][4][17];
    __shared__ float zr[16][4];
#pragma unroll
    for (int b = 0; b < 4; ++b) red[seg][b][o] = sacc[b];
    if (o == 0) {
#pragma unroll
        for (int b = 0; b < 4; ++b) zr[seg][b] = zacc[b];
    }
    __syncthreads();
    if (tid < 64) {
        int b = tid >> 4, oo = tid & 15;
        float t = 0.f;
#pragma unroll
        for (int i = 0; i < 16; ++i) t += red[i][b][oo];
        atomicAdd(&s_out[((size_t)c * 128 + b0 + b) * 16 + oo], t);
    } else if (z_out && tid < 68) {
        int b = tid - 64;
        float t = 0.f;
#pragma unroll
        for (int i = 0; i < 16; ++i) t += zr[i][b];
        atomicAdd(&z_out[(size_t)c * 128 + b0 + b], t);
    }
}

// ---------------- final: v = squash(s/z, axis=batch) -> out[b,c,o] ----------------------
__global__ __launch_bounds__(128) void squash_final(
    const float* __restrict__ s, const float* __restrict__ z,
    float* __restrict__ out)
{
    const int c = blockIdx.x, b = threadIdx.x;   // 10 blocks, 128 threads
    float sv[16];
    const float* sp = s + ((size_t)c * 128 + b) * 16;
    float zin = 1.f / z[c * 128 + b];
#pragma unroll
    for (int o = 0; o < 16; ++o) sv[o] = sp[o] * zin;
    __shared__ float m[16][129];
#pragma unroll
    for (int o = 0; o < 16; ++o) m[o][b] = sv[o] * sv[o];
    __syncthreads();
    __shared__ float sn[16];
    if (b < 16) {
        float t = 0.f;
        for (int i = 0; i < 128; ++i) t += m[b][i];
        sn[b] = t;
    }
    __syncthreads();
#pragma unroll
    for (int o = 0; o < 16; ++o) {
        float scale = sqrtf(sn[o]) / (1.f + sn[o]);
        out[((size_t)b * 10 + c) * 16 + o] = sv[o] * scale;
    }
}

// ---------------- launch ----------------------------------------------------------------
extern "C" void kernel_launch(void* const* d_in, const int* in_sizes, int n_in,
                              void* d_out, int out_size, void* d_ws, size_t ws_size,
                              hipStream_t stream)
{
    (void)in_sizes; (void)n_in; (void)out_size; (void)ws_size;
    const float* inp = (const float*)d_in[0];
    const float* cw  = (const float*)d_in[1];
    const float* cb  = (const float*)d_in[2];
    const float* rw  = (const float*)d_in[3];
    float* out = (float*)d_out;

    // workspace layout (bytes), total ~73.1 MB:
    //   [0, 33.0M)        part f16 [14,4608,256]   (conv -> combine)
    //   [33.0M, 59.2M)    in_t f16 (conv-time); xh f16 [128,1152,8] aliases after conv
    //   [59.2M, 69.9M)    w_t f16 (conv-time only)
    //   [69.9M, 72.8M)    rwh f16 [10,1152,16,8]
    //   [72.8M, 73.1M)    s0,s1,s2 (3x81920) z1,z2 (2x5120)
    char* ws = (char*)d_ws;
    f16*   part = (f16*)(ws);                       // 33,030,144
    f16*   in_t = (f16*)(ws + 33030144);            // 26,214,400
    f16*   w_t  = (f16*)(ws + 59244544);            // 10,616,832 -> 69,861,376
    f16*   xh   = (f16*)(ws + 33030144);            //  2,359,296 (aliases dead in_t)
    f16*   rwh  = (f16*)(ws + 69861376);            //  2,949,120 -> 72,810,496
    float* s0   = (float*)(ws + 72810496);          //     81,920
    float* s1   = (float*)(ws + 72892416);          //     81,920
    float* s2   = (float*)(ws + 72974336);          //     81,920
    float* z1   = (float*)(ws + 73056256);          //      5,120
    float* z2   = (float*)(ws + 73061376);          //      5,120 -> 73,066,496

    // zero all routing accumulators (s0..s2,z1,z2 contiguous = 256 KB)
    hipMemsetAsync(s0, 0, 3 * 81920 + 2 * 5120, stream);

    transpose_input<<<dim3(128, 8, 13), dim3(32, 8), 0, stream>>>(inp, in_t);
    permute_w<<<256, 256, 0, stream>>>(cw, w_t);
    permute_rw<<<1440, 256, 0, stream>>>(rw, rwh);
    conv_mfma<<<dim3(36, 1, SPLITK), 256, 0, stream>>>(in_t, w_t, part);
    combine_squash<<<144, 256, 0, stream>>>(part, cb, xh);

    // routing: pred recomputed on the fly; v folded into each iteration's preamble
    route_it<<<1280, 256, 0, stream>>>(xh, rwh, nullptr, nullptr, nullptr, nullptr,
                                       s0, nullptr);                        // iter 0
    route_it<<<1280, 256, 0, stream>>>(xh, rwh, s0, nullptr, nullptr, nullptr,
                                       s1, z1);                             // iter 1 (v0)
    route_it<<<1280, 256, 0, stream>>>(xh, rwh, s0, nullptr, s1, z1,
                                       s2, z2);                             // iter 2 (v0+v1)
    squash_final<<<10, 128, 0, stream>>>(s2, z2, out);
}

// Round 7
// 241.020 us; speedup vs baseline: 1.7613x; 1.1172x over previous
//
#include <hip/hip_runtime.h>
#include <math.h>

typedef _Float16 f16;
typedef _Float16 f16x4 __attribute__((ext_vector_type(4)));
typedef _Float16 f16x8 __attribute__((ext_vector_type(8)));
typedef float f32x4 __attribute__((ext_vector_type(4)));
typedef float f32x8 __attribute__((ext_vector_type(8)));

#define AS1 __attribute__((address_space(1)))
#define AS3 __attribute__((address_space(3)))

__device__ __forceinline__ void gld_lds16(const f16* g, f16* l) {
#if defined(__has_builtin) && __has_builtin(__builtin_amdgcn_global_load_lds)
    __builtin_amdgcn_global_load_lds((const AS1 void*)g, (AS3 void*)l, 16, 0, 0);
#else
    *(uint4*)l = *(const uint4*)g;
#endif
}

// ---------------- pre-pass 1: input [128,256,20,20] f32 -> [128,20,20,256] f16 ----------
__global__ __launch_bounds__(256) void transpose_input(
    const float* __restrict__ inp, f16* __restrict__ out)
{
    const int b = blockIdx.x, c0 = blockIdx.y * 32, p0 = blockIdx.z * 32;
    const int tx = threadIdx.x, ty = threadIdx.y;   // 32 x 8
    __shared__ float t[32][33];
#pragma unroll
    for (int j = 0; j < 4; ++j) {
        int c = ty + j * 8, p = p0 + tx;
        if (p < 400) t[c][tx] = inp[((size_t)b * 256 + c0 + c) * 400 + p];
    }
    __syncthreads();
#pragma unroll
    for (int j = 0; j < 4; ++j) {
        int p = p0 + ty + j * 8;
        if (p < 400) out[((size_t)b * 400 + p) * 256 + c0 + tx] = (f16)t[tx][ty + j * 8];
    }
}

// ---------------- pre-pass 2: conv_w [n=256][cin=256][p=81] f32 -> w_t[n][p*256+cin] f16 -
__global__ __launch_bounds__(256) void permute_w(
    const float* __restrict__ cw, f16* __restrict__ w_t)
{
    const int n = blockIdx.x, t = threadIdx.x;
    __shared__ f16 buf[81 * 258];
    const float* src = cw + (size_t)n * 20736;
    for (int i = t; i < 20736; i += 256) {
        int cin = i / 81, p = i - cin * 81;
        buf[p * 258 + cin] = (f16)src[i];
    }
    __syncthreads();
    f16* dst = w_t + (size_t)n * 20736;
    for (int j = t; j < 20736; j += 256) {
        int p = j >> 8, cin = j & 255;
        dst[j] = buf[p * 258 + cin];
    }
}

// ---------------- pre-pass 3: rw [10,1152,8,16] f32 -> rwh [10,1152,16,8] f16 ------------
__global__ __launch_bounds__(256) void permute_rw(
    const float* __restrict__ rw, f16* __restrict__ rwh)
{
    int g = blockIdx.x * 256 + threadIdx.x;      // over 10*1152*32 = 368640
    int cr = g >> 5, rem = g & 31;               // cr: (c,r) pair
    int o = rem >> 1, h = (rem & 1) * 4;
    const float* src = rw + (size_t)cr * 128 + o;
    f16x4 v;
#pragma unroll
    for (int j = 0; j < 4; ++j) v[j] = (f16)src[(h + j) * 16];
    *(f16x4*)(rwh + (size_t)cr * 128 + o * 8 + h) = v;
}

// ---------------- conv as implicit-im2col MFMA GEMM, 2-phase interleaved pipeline ------
// (UNCHANGED — measured ~61 us, MfmaUtil ~33.)
#define SPLITK 14
__global__ __launch_bounds__(256, 2) void conv_mfma(
    const f16* __restrict__ in_t,   // [128,20,20,256]
    const f16* __restrict__ w_t,    // [256,20736]
    f16* __restrict__ part)         // [14,4608,256] f16
{
    __shared__ f16 As[3][128 * 32];
    __shared__ f16 Bs[3][256 * 32];
    const int tid = threadIdx.x;
    const int lane = tid & 63, wave = tid >> 6;
    const int wm = wave >> 1, wn = wave & 1;

    const int bid = blockIdx.x + 36 * blockIdx.z;
    const int wgid = (bid & 7) * 63 + (bid >> 3);
    const int m0 = (wgid % 36) * 128;
    const int kz = wgid / 36;

    const int kc0 = kz * 46 + (kz < 4 ? kz : 4);
    const int NT  = (kz < 4) ? 47 : 46;

    int srcA[2], srcB[4];
#pragma unroll
    for (int i = 0; i < 2; ++i) {
        int pairp = i * 32 + (tid >> 3);
        int chunk8 = (tid & 7) ^ (pairp & 7);
        int e = chunk8 >> 2, q4 = chunk8 & 3;
        int m = m0 + pairp * 2 + e;
        int b = m / 36, hw = m - b * 36;
        int ho = hw / 6, wo = hw - ho * 6;
        srcA[i] = ((b * 20 + 2 * ho) * 20 + 2 * wo) * 256 + q4 * 8;
    }
#pragma unroll
    for (int i = 0; i < 4; ++i) {
        int pairp = i * 32 + (tid >> 3);
        int chunk8 = (tid & 7) ^ (pairp & 7);
        int e = chunk8 >> 2, q4 = chunk8 & 3;
        int n = pairp * 2 + e;
        srcB[i] = n * 20736 + q4 * 8;
    }

    const int row = lane & 15, quad = lane >> 4;
    int offA[4], offB[8];
#pragma unroll
    for (int mt = 0; mt < 4; ++mt) {
        int m = wm * 64 + mt * 16 + row;
        int ph8 = (((m & 1) << 2) + quad) ^ ((m >> 1) & 7);
        offA[mt] = (m >> 1) * 64 + ph8 * 8;
    }
#pragma unroll
    for (int nt = 0; nt < 8; ++nt) {
        int n = wn * 128 + nt * 16 + row;
        int ph8 = (((n & 1) << 2) + quad) ^ ((n >> 1) & 7);
        offB[nt] = (n >> 1) * 64 + ph8 * 8;
    }

    f32x4 acc[4][8] = {};

#define KOFFS(T) int kc = kc0 + (T); int pp = kc >> 3, cq = kc & 7;           \
    int kh = pp / 9, kw = pp - kh * 9;                                        \
    int koffA = (kh * 20 + kw) * 256 + cq * 32; int koffB = kc * 32;
#define STAGE1(T, BUF) do { KOFFS(T)                                          \
        gld_lds16(in_t + srcA[0] + koffA, &As[BUF][tid * 8]);                 \
        gld_lds16(in_t + srcA[1] + koffA, &As[BUF][2048 + tid * 8]);          \
        gld_lds16(w_t + srcB[0] + koffB, &Bs[BUF][tid * 8]);                  \
    } while (0)
#define STAGE2(T, BUF) do { KOFFS(T)                                          \
        gld_lds16(w_t + srcB[1] + koffB, &Bs[BUF][2048 + tid * 8]);           \
        gld_lds16(w_t + srcB[2] + koffB, &Bs[BUF][4096 + tid * 8]);           \
        gld_lds16(w_t + srcB[3] + koffB, &Bs[BUF][6144 + tid * 8]);           \
    } while (0)

    STAGE1(0, 0); STAGE2(0, 0);
    STAGE1(1, 1); STAGE2(1, 1);
    asm volatile("s_waitcnt vmcnt(6)" ::: "memory");
    __builtin_amdgcn_s_barrier();

    int buf = 0;
    for (int t = 0; t < NT; ++t) {
        const f16* Ab = &As[buf][0];
        const f16* Bb = &Bs[buf][0];
        int bn = buf + 2; if (bn >= 3) bn -= 3;
        f16x8 af[4], bfr[8];

        // ---------------- phase A: af[0..3], bfr[0..3] -> acc[*][0..3] ----------------
#pragma unroll
        for (int mt = 0; mt < 4; ++mt) af[mt] = *(const f16x8*)(Ab + offA[mt]);
#pragma unroll
        for (int nt = 0; nt < 4; ++nt) bfr[nt] = *(const f16x8*)(Bb + offB[nt]);
        if (t + 2 < NT) STAGE1(t + 2, bn);
        __builtin_amdgcn_s_barrier();
        asm volatile("s_waitcnt lgkmcnt(0)" ::: "memory");
        __builtin_amdgcn_sched_barrier(0);
        __builtin_amdgcn_s_setprio(1);
#pragma unroll
        for (int mt = 0; mt < 4; ++mt)
#pragma unroll
            for (int nt = 0; nt < 4; ++nt)
                acc[mt][nt] = __builtin_amdgcn_mfma_f32_16x16x32_f16(
                    af[mt], bfr[nt], acc[mt][nt], 0, 0, 0);
        __builtin_amdgcn_s_setprio(0);
        __builtin_amdgcn_s_barrier();

        // ---------------- phase B: bfr[4..7] -> acc[*][4..7] --------------------------
#pragma unroll
        for (int nt = 4; nt < 8; ++nt) bfr[nt] = *(const f16x8*)(Bb + offB[nt]);
        if (t + 2 < NT) STAGE2(t + 2, bn);
        if (t + 2 < NT)
            asm volatile("s_waitcnt vmcnt(6)" ::: "memory");
        else if (t + 1 < NT)
            asm volatile("s_waitcnt vmcnt(0)" ::: "memory");
        __builtin_amdgcn_s_barrier();
        asm volatile("s_waitcnt lgkmcnt(0)" ::: "memory");
        __builtin_amdgcn_sched_barrier(0);
        __builtin_amdgcn_s_setprio(1);
#pragma unroll
        for (int mt = 0; mt < 4; ++mt)
#pragma unroll
            for (int nt = 4; nt < 8; ++nt)
                acc[mt][nt] = __builtin_amdgcn_mfma_f32_16x16x32_f16(
                    af[mt], bfr[nt], acc[mt][nt], 0, 0, 0);
        __builtin_amdgcn_s_setprio(0);
        __builtin_amdgcn_s_barrier();

        if (++buf == 3) buf = 0;
    }
#undef STAGE1
#undef STAGE2
#undef KOFFS

    const int col = lane & 15, qr = (lane >> 4) * 4;
    f16* pb = part + (size_t)kz * 4608 * 256;
#pragma unroll
    for (int mt = 0; mt < 4; ++mt)
#pragma unroll
        for (int rg = 0; rg < 4; ++rg) {
            int m = m0 + wm * 64 + mt * 16 + qr + rg;
#pragma unroll
            for (int nt = 0; nt < 8; ++nt) {
                int n = wn * 128 + nt * 16 + col;
                pb[(size_t)m * 256 + n] = (f16)acc[mt][nt][rg];
            }
        }
}

// ---------------- split-K reduce + bias + capsule squash -> xh[128,1152,8] f16 ----------
__global__ __launch_bounds__(256) void combine_squash(
    const f16* __restrict__ part, const float* __restrict__ bias,
    f16* __restrict__ xh)
{
    int idx = blockIdx.x * 256 + threadIdx.x;   // over 4608*8
    int m = idx >> 3, g = idx & 7;              // g: group of 4 o's
    int b = m / 36, hw = m - b * 36;
    float val[8][4];
#pragma unroll
    for (int k = 0; k < 8; ++k)
#pragma unroll
        for (int j = 0; j < 4; ++j) val[k][j] = bias[k * 32 + g * 4 + j];
#pragma unroll
    for (int s = 0; s < SPLITK; ++s) {
        const f16* p = part + ((size_t)s * 4608 + m) * 256 + g * 4;
#pragma unroll
        for (int k = 0; k < 8; ++k) {
            f16x4 v = *(const f16x4*)(p + k * 32);
#pragma unroll
            for (int j = 0; j < 4; ++j) val[k][j] += (float)v[j];
        }
    }
#pragma unroll
    for (int j = 0; j < 4; ++j) {
        float sn = 0.f;
#pragma unroll
        for (int k = 0; k < 8; ++k) sn += val[k][j] * val[k][j];
        float scale = sqrtf(sn) / (1.f + sn);
        int r = (g * 4 + j) * 36 + hw;
        f16x8 hv;
#pragma unroll
        for (int k = 0; k < 8; ++k) hv[k] = (f16)(val[k][j] * scale);
        *(f16x8*)(xh + ((size_t)b * 1152 + r) * 8) = hv;
    }
}

// ---------------- pred (f16, materialized) + fused routing-iter-0 s-accumulation --------
// pred[c,b,r,o] = sum_k xh[b,r,k]*rwh[c,r,o,k]; s0[c,b,o] += sum_r pred. s0 pre-zeroed.
// R2's verified pred_s0 pattern with f16 inputs. Grid (10,36,4), 256 thr:
// o = tid&15, rp = tid>>4 handles r-pair (r, r+1).
__global__ __launch_bounds__(256) void pred_s0h(
    const f16* __restrict__ xh,     // [128,1152,8]
    const f16* __restrict__ rwh,    // [10,1152,16,8]
    f16* __restrict__ pred,         // [10,128,1152,16]
    float* __restrict__ s0)         // [10,128,16] pre-zeroed
{
    const int c = blockIdx.x, r0 = blockIdx.y * 32, b0 = blockIdx.z * 32;
    const int tid = threadIdx.x;
    const int o = tid & 15, rp = tid >> 4;
    const int r = r0 + rp * 2;

    __shared__ float s_sh[32 * 16];
    s_sh[tid] = 0.f; s_sh[tid + 256] = 0.f;

    f16x8 w0h = *(const f16x8*)(rwh + ((size_t)(c * 1152 + r) * 16 + o) * 8);
    f16x8 w1h = *(const f16x8*)(rwh + ((size_t)(c * 1152 + r + 1) * 16 + o) * 8);
    f32x8 W0 = __builtin_convertvector(w0h, f32x8);
    f32x8 W1 = __builtin_convertvector(w1h, f32x8);
    __syncthreads();

    for (int bb = 0; bb < 32; ++bb) {
        const int b = b0 + bb;
        f16x8 x0h = *(const f16x8*)(xh + ((size_t)b * 1152 + r) * 8);
        f16x8 x1h = *(const f16x8*)(xh + ((size_t)b * 1152 + r + 1) * 8);
        f32x8 X0 = __builtin_convertvector(x0h, f32x8);
        f32x8 X1 = __builtin_convertvector(x1h, f32x8);
        float p0 = X0[0]*W0[0] + X0[1]*W0[1] + X0[2]*W0[2] + X0[3]*W0[3]
                 + X0[4]*W0[4] + X0[5]*W0[5] + X0[6]*W0[6] + X0[7]*W0[7];
        float p1 = X1[0]*W1[0] + X1[1]*W1[1] + X1[2]*W1[2] + X1[3]*W1[3]
                 + X1[4]*W1[4] + X1[5]*W1[5] + X1[6]*W1[6] + X1[7]*W1[7];
        f16* pb = pred + ((size_t)(c * 128 + b) * 1152 + r) * 16 + o;
        pb[0]  = (f16)p0;
        pb[16] = (f16)p1;
        // iter-0 accumulation: sum over this block's 32 routes
        float ps = p0 + p1;
        ps += __shfl_xor(ps, 16);
        ps += __shfl_xor(ps, 32);           // lanes 0-15: sum over wave's 4 r-pairs
        if ((tid & 63) < 16) atomicAdd(&s_sh[bb * 16 + o], ps);
    }
    __syncthreads();
    for (int i = tid; i < 512; i += 256) {
        int bb = i >> 4, oo = i & 15;
        atomicAdd(&s0[((size_t)c * 128 + b0 + bb) * 16 + oo], s_sh[i]);
    }
}

// ---------------- routing iteration: lean pred stream, register-local o ----------------
// vs = squash_batch(sa,za)[b] (+ squash_batch(sb2,zb2)[b] if sb2) — parallel preamble.
// za/zb2 null -> z = 1152. Main: per r, t = pred[r,:].vs (register-local), e = exp(t),
// sacc += e*pred, zacc += e. LDS tree reduce -> s_out/z_out (one block per (c,b)).
__global__ __launch_bounds__(256) void route_f16v(
    const f16* __restrict__ pred,
    const float* __restrict__ sa, const float* __restrict__ za,
    const float* __restrict__ sb2, const float* __restrict__ zb2,
    float* __restrict__ s_out,      // [10,128,16]
    float* __restrict__ z_out)      // [10,128]
{
    const int c = blockIdx.x, b = blockIdx.y, tid = threadIdx.x;
    const size_t base = (size_t)(c * 128 + b) * 1152;
    const int o = tid & 15, seg = tid >> 4;

    __shared__ float lred[16][17];
    __shared__ float vs[16];

#define VSADD(S, Z) do {                                                      \
        float part_ = 0.f;                                                    \
        _Pragma("unroll")                                                     \
        for (int j = 0; j < 8; ++j) {                                         \
            int bb = seg * 8 + j;                                             \
            float zin = (Z) ? 1.f / (Z)[c * 128 + bb] : (1.f / 1152.f);       \
            float q = (S)[((size_t)c * 128 + bb) * 16 + o] * zin;             \
            part_ += q * q;                                                   \
        }                                                                     \
        lred[seg][o] = part_;                                                 \
        __syncthreads();                                                      \
        if (tid < 16) {                                                       \
            float t_ = 0.f;                                                   \
            _Pragma("unroll")                                                 \
            for (int i = 0; i < 16; ++i) t_ += lred[i][tid];                  \
            float zin = (Z) ? 1.f / (Z)[c * 128 + b] : (1.f / 1152.f);        \
            vs[tid] += (S)[((size_t)c * 128 + b) * 16 + tid] * zin *          \
                       sqrtf(t_) / (1.f + t_);                                \
        }                                                                     \
        __syncthreads();                                                      \
    } while (0)

    if (tid < 16) vs[tid] = 0.f;
    __syncthreads();
    VSADD(sa, za);
    if (sb2) VSADD(sb2, zb2);
#undef VSADD

    float vr[16];
#pragma unroll
    for (int j = 0; j < 16; ++j) vr[j] = vs[j];

    float sacc[16];
#pragma unroll
    for (int j = 0; j < 16; ++j) sacc[j] = 0.f;
    float zacc = 0.f;

    for (int r = tid; r < 1152; r += 256) {
        const f16x8* pp = (const f16x8*)(pred + (base + r) * 16);
        f32x8 q0 = __builtin_convertvector(pp[0], f32x8);
        f32x8 q1 = __builtin_convertvector(pp[1], f32x8);
        float t = 0.f;
#pragma unroll
        for (int j = 0; j < 8; ++j) t += q0[j] * vr[j] + q1[j] * vr[j + 8];
        float e = __expf(t);
#pragma unroll
        for (int j = 0; j < 8; ++j) { sacc[j] += e * q0[j]; sacc[j + 8] += e * q1[j]; }
        zacc += e;
    }

    __shared__ float red[256][16];
    __shared__ float red2[16][16];
    __shared__ float zred[256];
    __shared__ float zpart[16];
#pragma unroll
    for (int j = 0; j < 16; ++j) red[tid][j] = sacc[j];
    zred[tid] = zacc;
    __syncthreads();
    {
        float t = 0.f;
#pragma unroll
        for (int j = 0; j < 16; ++j) t += red[seg * 16 + j][o];
        red2[seg][o] = t;
        if (tid < 16) {
            float tz = 0.f;
#pragma unroll
            for (int j = 0; j < 16; ++j) tz += zred[tid * 16 + j];
            zpart[tid] = tz;
        }
    }
    __syncthreads();
    if (tid < 16) {
        float t = 0.f;
#pragma unroll
        for (int sg = 0; sg < 16; ++sg) t += red2[sg][tid];
        s_out[(size_t)(c * 128 + b) * 16 + tid] = t;
    } else if (tid == 16) {
        float tz = 0.f;
#pragma unroll
        for (int j = 0; j < 16; ++j) tz += zpart[j];
        z_out[c * 128 + b] = tz;
    }
}

// ---------------- final: v = squash(s/z, axis=batch) -> out[b,c,o] ----------------------
__global__ __launch_bounds__(128) void squash_final(
    const float* __restrict__ s, const float* __restrict__ z,
    float* __restrict__ out)
{
    const int c = blockIdx.x, b = threadIdx.x;   // 10 blocks, 128 threads
    float sv[16];
    const float* sp = s + ((size_t)c * 128 + b) * 16;
    float zin = 1.f / z[c * 128 + b];
#pragma unroll
    for (int o = 0; o < 16; ++o) sv[o] = sp[o] * zin;
    __shared__ float m[16][129];
#pragma unroll
    for (int o = 0; o < 16; ++o) m[o][b] = sv[o] * sv[o];
    __syncthreads();
    __shared__ float sn[16];
    if (b < 16) {
        float t = 0.f;
        for (int i = 0; i < 128; ++i) t += m[b][i];
        sn[b] = t;
    }
    __syncthreads();
#pragma unroll
    for (int o = 0; o < 16; ++o) {
        float scale = sqrtf(sn[o]) / (1.f + sn[o]);
        out[((size_t)b * 10 + c) * 16 + o] = sv[o] * scale;
    }
}

// ---------------- launch ----------------------------------------------------------------
extern "C" void kernel_launch(void* const* d_in, const int* in_sizes, int n_in,
                              void* d_out, int out_size, void* d_ws, size_t ws_size,
                              hipStream_t stream)
{
    (void)in_sizes; (void)n_in; (void)out_size; (void)ws_size;
    const float* inp = (const float*)d_in[0];
    const float* cw  = (const float*)d_in[1];
    const float* cb  = (const float*)d_in[2];
    const float* rw  = (const float*)d_in[3];
    float* out = (float*)d_out;

    // workspace layout (bytes), total ~75.4 MB:
    //   [0, 33.0M)        part f16 (conv -> combine); pred f16 [10,128,1152,16] (47.2 MB)
    //                     aliases [0,47.2M) AFTER combine (part + in_t prefix both dead)
    //   [33.0M, 59.2M)    in_t f16 (conv-time only)
    //   [59.2M, 69.9M)    w_t f16 (conv-time only)
    //   [69.9M, 72.8M)    rwh f16 [10,1152,16,8]
    //   [72.8M, 75.2M)    xh f16 [128,1152,8]
    //   [75.2M, 75.4M)    s0,sB,sC (3x81920) zB,zC (2x5120)
    char* ws = (char*)d_ws;
    f16*   part = (f16*)(ws);                       // 33,030,144
    f16*   pred = (f16*)(ws);                       // 47,185,920 (alias, post-combine)
    f16*   in_t = (f16*)(ws + 33030144);            // 26,214,400
    f16*   w_t  = (f16*)(ws + 59244544);            // 10,616,832 -> 69,861,376
    f16*   rwh  = (f16*)(ws + 69861376);            //  2,949,120 -> 72,810,496
    f16*   xh   = (f16*)(ws + 72810496);            //  2,359,296 -> 75,169,792
    float* s0   = (float*)(ws + 75169792);          //     81,920
    float* sB   = (float*)(ws + 75251712);          //     81,920
    float* sC   = (float*)(ws + 75333632);          //     81,920
    float* zB   = (float*)(ws + 75415552);          //      5,120
    float* zC   = (float*)(ws + 75420672);          //      5,120 -> 75,425,792

    hipMemsetAsync(s0, 0, 81920, stream);

    transpose_input<<<dim3(128, 8, 13), dim3(32, 8), 0, stream>>>(inp, in_t);
    permute_w<<<256, 256, 0, stream>>>(cw, w_t);
    permute_rw<<<1440, 256, 0, stream>>>(rw, rwh);
    conv_mfma<<<dim3(36, 1, SPLITK), 256, 0, stream>>>(in_t, w_t, part);
    combine_squash<<<144, 256, 0, stream>>>(part, cb, xh);

    // pred materialized once (f16); iter-0 s fused into the pred pass
    pred_s0h<<<dim3(10, 36, 4), 256, 0, stream>>>(xh, rwh, pred, s0);

    // iters 1,2: lean pred streams, register-local o (telescoped logits: vs = v0(+v1))
    route_f16v<<<dim3(10, 128), 256, 0, stream>>>(pred, s0, nullptr, nullptr, nullptr,
                                                  sB, zB);                  // iter 1
    route_f16v<<<dim3(10, 128), 256, 0, stream>>>(pred, s0, nullptr, sB, zB,
                                                  sC, zC);                  // iter 2
    squash_final<<<10, 128, 0, stream>>>(sC, zC, out);
}